// Round 1
// 3122.200 us; speedup vs baseline: 2.4880x; 2.4880x over previous
//
#include <hip/hip_runtime.h>
#include <math.h>

constexpr int SEQ   = 2048;
constexpr int DIM   = 1024;
constexpr int NHQ   = 16;
constexpr int NKV   = 4;
constexpr int DH    = 64;
constexpr int FFN   = 4096;
constexpr int VOCAB = 32000;
constexpr int LAY   = 4;
constexpr float REPS = 1e-6f;
constexpr int QKVD  = NHQ * DH + 2 * NKV * DH;   // 1536 fused q|k|v width

typedef __attribute__((ext_vector_type(8))) short bfrag_t;   // 8 bf16 = 4 VGPR
typedef __attribute__((ext_vector_type(4))) float facc_t;    // 4 f32 acc

__device__ __forceinline__ ushort f2bf(float f) {            // RNE fp32->bf16
    unsigned u = __float_as_uint(f);
    u += 0x7fffu + ((u >> 16) & 1u);
    return (ushort)(u >> 16);
}

__device__ __forceinline__ void gll16(const void* g, void* l) {
    __builtin_amdgcn_global_load_lds((__attribute__((address_space(1))) void*)g,
                                     (__attribute__((address_space(3))) void*)l,
                                     16, 0, 0);
}

// ---------------- RoPE tables (fp64 trig for accuracy) ----------------
__global__ void k_rope_table(float* __restrict__ ct, float* __restrict__ st) {
    int idx = blockIdx.x * 256 + threadIdx.x;      // SEQ*32 total
    int s = idx >> 5, j = idx & 31;
    double invf = exp(-2.0 * (double)j / (double)DH * log(10000.0));
    double ang  = (double)s * invf;
    ct[idx] = (float)cos(ang);
    st[idx] = (float)sin(ang);
}

// ---------------- embedding gather ----------------
__global__ void k_embed(const float* __restrict__ emb, const int* __restrict__ ids,
                        float* __restrict__ h) {
    int s = blockIdx.x, t = threadIdx.x;
    const float4* src = (const float4*)(emb + (size_t)ids[s] * DIM);
    float4*       dst = (float4*)(h + (size_t)s * DIM);
    dst[t] = src[t];
}

// ---------------- RMSNorm: fp32 in, bf16 out ----------------
__global__ void k_rmsnorm(const float* __restrict__ h, const float* __restrict__ w,
                          ushort* __restrict__ x) {
    int s = blockIdx.x, t = threadIdx.x;
    float4 v = ((const float4*)(h + (size_t)s * DIM))[t];
    float ss = v.x*v.x + v.y*v.y + v.z*v.z + v.w*v.w;
    #pragma unroll
    for (int off = 32; off; off >>= 1) ss += __shfl_down(ss, off, 64);
    __shared__ float red[4];
    int wid = t >> 6, lane = t & 63;
    if (lane == 0) red[wid] = ss;
    __syncthreads();
    float tot = red[0] + red[1] + red[2] + red[3];
    float rs = rsqrtf(tot / (float)DIM + REPS);
    float4 wf = ((const float4*)w)[t];
    ushort4 o;
    o.x = f2bf(wf.x * v.x * rs); o.y = f2bf(wf.y * v.y * rs);
    o.z = f2bf(wf.z * v.z * rs); o.w = f2bf(wf.w * v.w * rs);
    ((ushort4*)(x + (size_t)s * DIM))[t] = o;
}

// ---------------- weight convert+transpose: W[K][N] f32 -> Wt[N][K] bf16 ----
__global__ void k_convT(const float* __restrict__ W, ushort* __restrict__ Wt,
                        int K, int N) {
    __shared__ float tile[32][33];
    int n0 = blockIdx.x << 5, k0 = blockIdx.y << 5;
    int tx = threadIdx.x, ty = threadIdx.y;        // 32 x 8
    #pragma unroll
    for (int i = 0; i < 32; i += 8)
        tile[ty + i][tx] = W[(size_t)(k0 + ty + i) * N + n0 + tx];
    __syncthreads();
    #pragma unroll
    for (int i = 0; i < 32; i += 8)
        Wt[(size_t)(n0 + ty + i) * K + k0 + tx] = f2bf(tile[tx][ty + i]);
}

// ---------------- concat q|k|v bias into one 1536 vector ----------------
__global__ void k_bias_cat(const float* __restrict__ qb, const float* __restrict__ kb,
                           const float* __restrict__ vb, float* __restrict__ o) {
    int t = blockIdx.x * 256 + threadIdx.x;
    if (t >= QKVD) return;
    if (t < NHQ * DH) o[t] = qb[t];
    else if (t < NHQ * DH + NKV * DH) o[t] = kb[t - NHQ * DH];
    else o[t] = vb[t - NHQ * DH - NKV * DH];
}

// ---------------- bf16 MFMA GEMM, m97 structure ----------------
// C[M,N] f32 (+bias)(+residual) = A[M,K]bf16 @ Bt[N,K]bf16^T
// 128x128 tile, BK=32, 256 thr = 4 waves (2x2), each wave 64x64 via 4x4
// mfma_f32_16x16x32_bf16 fragments. Staging via global_load_lds width=16
// into linear LDS (16 KB). Requires M%128==0, N%128==0, K%32==0.
template<int ADD_BIAS, int RESIDUAL>
__global__ __launch_bounds__(256) void k_gemm_bf(
        const ushort* __restrict__ A, const ushort* __restrict__ Bt,
        const float* __restrict__ bias, float* __restrict__ C,
        int M, int N, int K) {
    __shared__ ushort sAB[8192];                   // [0,4096): A[128][32]  [4096,8192): B[128][32]
    const int t = threadIdx.x;
    const int w = t >> 6, l = t & 63;
    const int bm = blockIdx.y << 7, bn = blockIdx.x << 7;

    // 16 chunks of 1KB per K-step; wave w stages chunks w, w+4, w+8, w+12.
    // LDS write is linear: chunk g, lane l -> byte g*1024 + l*16.
    const ushort* gsrc[4];
    ushort* ldst[4];
    #pragma unroll
    for (int i = 0; i < 4; i++) {
        int g = (i << 2) + w;
        int o = g * 1024 + l * 16;                 // byte offset in 16KB stage
        ldst[i] = sAB + g * 512;                   // wave-uniform base (ushorts)
        if (o < 8192) {                            // A chunk: row=o/64, k=(o%64)/2
            int row = o >> 6, kc = (o & 63) >> 1;
            gsrc[i] = A + (size_t)(bm + row) * K + kc;
        } else {                                   // B chunk
            int o2 = o - 8192;
            int row = o2 >> 6, kc = (o2 & 63) >> 1;
            gsrc[i] = Bt + (size_t)(bn + row) * K + kc;
        }
    }

    const int lr = l & 15, lk = (l >> 4) << 3;     // frag row/col, frag k-base
    const int wr = (w >> 1) << 6, wc = (w & 1) << 6;
    const ushort* sA = sAB;
    const ushort* sB = sAB + 4096;

    facc_t acc[4][4] = {};
    for (int k0 = 0; k0 < K; k0 += 32) {
        __syncthreads();                           // LDS free to overwrite
        #pragma unroll
        for (int i = 0; i < 4; i++) gll16(gsrc[i], ldst[i]);
        #pragma unroll
        for (int i = 0; i < 4; i++) gsrc[i] += 32;
        __syncthreads();                           // vmcnt(0) drained by compiler

        bfrag_t af[4], bfr[4];
        #pragma unroll
        for (int m = 0; m < 4; m++)
            af[m] = *(const bfrag_t*)(sA + (wr + (m << 4) + lr) * 32 + lk);
        #pragma unroll
        for (int n = 0; n < 4; n++)
            bfr[n] = *(const bfrag_t*)(sB + (wc + (n << 4) + lr) * 32 + lk);
        #pragma unroll
        for (int m = 0; m < 4; m++)
            #pragma unroll
            for (int n = 0; n < 4; n++)
                acc[m][n] = __builtin_amdgcn_mfma_f32_16x16x32_bf16(
                                af[m], bfr[n], acc[m][n], 0, 0, 0);
    }

    // C/D layout: col = lane&15, row = 4*(lane>>4) + r   [m89/m91 verified]
    const int li = (l >> 4) << 2;
    #pragma unroll
    for (int n = 0; n < 4; n++) {
        const int col = bn + wc + (n << 4) + lr;
        const float bv = ADD_BIAS ? bias[col] : 0.f;
        #pragma unroll
        for (int m = 0; m < 4; m++) {
            const int row0 = bm + wr + (m << 4) + li;
            #pragma unroll
            for (int r = 0; r < 4; r++) {
                float* cp = C + (size_t)(row0 + r) * N + col;
                float vv = acc[m][n][r] + bv;
                if (RESIDUAL) vv += *cp;
                *cp = vv;
            }
        }
    }
}

// ---------------- RoPE apply in-place on fused qkv (fp32) ----------------
__global__ void k_rope(float* __restrict__ qkv, const float* __restrict__ ct,
                       const float* __restrict__ st) {
    int s = blockIdx.x, t = threadIdx.x;
    float* row = qkv + (size_t)s * QKVD;
    for (int p = t; p < (NHQ + NKV) * 32; p += 256) {
        int hh = p >> 5, j = p & 31;
        float c = ct[s*32 + j], sn = st[s*32 + j];
        float* b = row + (hh < NHQ ? hh * DH : NHQ * DH + (hh - NHQ) * DH);
        float x1 = b[j], x2 = b[j + 32];
        b[j]      = x1 * c - x2 * sn;
        b[j + 32] = x2 * c + x1 * sn;
    }
}

// ---------------- flash attention, fp32 compute, bf16 output ----------------
__global__ __launch_bounds__(256) void k_attn(
        const float* __restrict__ qkv, ushort* __restrict__ ob) {
    __shared__ float Qs[64][68];
    __shared__ float Ks[64][68];   // reused as Ps[c][r]
    __shared__ float Vs[64][68];
    __shared__ float red[64][17];
    __shared__ float row_m[64], row_l[64], row_al[64];
    float (*Ps)[68] = Ks;

    int t  = threadIdx.x;
    int tx = t & 15, ty = t >> 4;
    int qt = blockIdx.x, hh = blockIdx.y;
    int kvh = hh >> 2;
    const float scale = 0.125f;
    const int koff = NHQ * DH + kvh * DH;
    const int voff = NHQ * DH + NKV * DH + kvh * DH;

    #pragma unroll
    for (int m = 0; m < 4; m++) {
        int idx = t + 256 * m;
        int r = idx >> 4, c4 = (idx & 15) << 2;
        float4 qv = *(const float4*)(qkv + (size_t)(qt*64 + r) * QKVD + hh*DH + c4);
        Qs[c4+0][r] = qv.x * scale; Qs[c4+1][r] = qv.y * scale;
        Qs[c4+2][r] = qv.z * scale; Qs[c4+3][r] = qv.w * scale;
    }
    if (t < 64) { row_m[t] = -INFINITY; row_l[t] = 0.f; }

    float oacc[4][4] = {};
    for (int kt = 0; kt <= qt; kt++) {
        __syncthreads();
        #pragma unroll
        for (int m = 0; m < 4; m++) {
            int idx = t + 256 * m;
            int r = idx >> 4, c4 = (idx & 15) << 2;
            float4 kv = *(const float4*)(qkv + (size_t)(kt*64 + r) * QKVD + koff + c4);
            Ks[c4+0][r] = kv.x; Ks[c4+1][r] = kv.y;
            Ks[c4+2][r] = kv.z; Ks[c4+3][r] = kv.w;
            *(float4*)&Vs[r][c4] = *(const float4*)(qkv + (size_t)(kt*64 + r) * QKVD + voff + c4);
        }
        __syncthreads();
        float sacc[4][4] = {};
        #pragma unroll
        for (int d = 0; d < 64; d++) {
            float a[4], b[4];
            *(float4*)a = *(const float4*)&Qs[d][ty << 2];
            *(float4*)b = *(const float4*)&Ks[d][tx << 2];
            #pragma unroll
            for (int i = 0; i < 4; i++)
                #pragma unroll
                for (int j = 0; j < 4; j++)
                    sacc[i][j] = fmaf(a[i], b[j], sacc[i][j]);
        }
        if (kt == qt) {
            #pragma unroll
            for (int i = 0; i < 4; i++)
                #pragma unroll
                for (int j = 0; j < 4; j++)
                    if ((tx << 2) + j > (ty << 2) + i) sacc[i][j] = -1e30f;
        }
        #pragma unroll
        for (int i = 0; i < 4; i++) {
            float mx = fmaxf(fmaxf(sacc[i][0], sacc[i][1]), fmaxf(sacc[i][2], sacc[i][3]));
            red[(ty << 2) + i][tx] = mx;
        }
        __syncthreads();
        if (t < 64) {
            float mt = red[t][0];
            #pragma unroll
            for (int u2 = 1; u2 < 16; u2++) mt = fmaxf(mt, red[t][u2]);
            float mo = row_m[t];
            float mn = fmaxf(mo, mt);
            row_al[t] = __expf(mo - mn);
            row_m[t]  = mn;
        }
        __syncthreads();
        #pragma unroll
        for (int i = 0; i < 4; i++) {
            float mn = row_m[(ty << 2) + i];
            float psum = 0.f;
            #pragma unroll
            for (int j = 0; j < 4; j++) {
                float p = __expf(sacc[i][j] - mn);
                Ps[(tx << 2) + j][(ty << 2) + i] = p;
                psum += p;
            }
            red[(ty << 2) + i][tx] = psum;
        }
        __syncthreads();
        if (t < 64) {
            float ssum = 0.f;
            #pragma unroll
            for (int u2 = 0; u2 < 16; u2++) ssum += red[t][u2];
            row_l[t] = row_al[t] * row_l[t] + ssum;
        }
        float al[4];
        #pragma unroll
        for (int i = 0; i < 4; i++) al[i] = row_al[(ty << 2) + i];
        #pragma unroll
        for (int i = 0; i < 4; i++)
            #pragma unroll
            for (int j = 0; j < 4; j++) oacc[i][j] *= al[i];
        #pragma unroll
        for (int c = 0; c < 64; c++) {
            float a[4], b[4];
            *(float4*)a = *(const float4*)&Ps[c][ty << 2];
            *(float4*)b = *(const float4*)&Vs[c][tx << 2];
            #pragma unroll
            for (int i = 0; i < 4; i++)
                #pragma unroll
                for (int j = 0; j < 4; j++)
                    oacc[i][j] = fmaf(a[i], b[j], oacc[i][j]);
        }
    }
    __syncthreads();
    #pragma unroll
    for (int i = 0; i < 4; i++) {
        int r = (ty << 2) + i;
        float inv = 1.0f / row_l[r];
        ushort4 ov;
        ov.x = f2bf(oacc[i][0] * inv); ov.y = f2bf(oacc[i][1] * inv);
        ov.z = f2bf(oacc[i][2] * inv); ov.w = f2bf(oacc[i][3] * inv);
        *(ushort4*)(ob + (size_t)(qt*64 + r) * (NHQ*DH) + hh*DH + (tx << 2)) = ov;
    }
}

// ---------------- silu(g)*u from fused gu buffer, bf16 out ----------------
__global__ void k_silu_mul_bf(const float* __restrict__ gu, ushort* __restrict__ gbf) {
    int i = blockIdx.x * 256 + threadIdx.x;        // SEQ*FFN/4 items
    int s = i >> 10, c = i & 1023;                 // FFN/4 = 1024
    float4 gv = ((const float4*)(gu + (size_t)s * 2 * FFN))[c];
    float4 uv = ((const float4*)(gu + (size_t)s * 2 * FFN + FFN))[c];
    ushort4 r;
    r.x = f2bf(gv.x / (1.f + __expf(-gv.x)) * uv.x);
    r.y = f2bf(gv.y / (1.f + __expf(-gv.y)) * uv.y);
    r.z = f2bf(gv.z / (1.f + __expf(-gv.z)) * uv.z);
    r.w = f2bf(gv.w / (1.f + __expf(-gv.w)) * uv.w);
    ((ushort4*)(gbf + (size_t)s * FFN))[c] = r;
}

extern "C" void kernel_launch(void* const* d_in, const int* in_sizes, int n_in,
                              void* d_out, int out_size, void* d_ws, size_t ws_size,
                              hipStream_t stream) {
    const float* emb    = (const float*)d_in[0];
    const float* ln1    = (const float*)d_in[1];
    const float* qw     = (const float*)d_in[2];
    const float* qbias  = (const float*)d_in[3];
    const float* kw     = (const float*)d_in[4];
    const float* kbias  = (const float*)d_in[5];
    const float* vw     = (const float*)d_in[6];
    const float* vbias  = (const float*)d_in[7];
    const float* ow     = (const float*)d_in[8];
    const float* ln2    = (const float*)d_in[9];
    const float* gw     = (const float*)d_in[10];
    const float* uw     = (const float*)d_in[11];
    const float* dw     = (const float*)d_in[12];
    const float* norm_w = (const float*)d_in[13];
    const float* lm_w   = (const float*)d_in[14];
    const int*   ids    = (const int*)d_in[15];
    float* out = (float*)d_out;

    // fp32 workspace
    float* ws       = (float*)d_ws;
    float* h        = ws;                                    // SEQ*DIM
    float* qkv      = h + (size_t)SEQ * DIM;                 // SEQ*QKVD
    float* gu       = qkv + (size_t)SEQ * QKVD;              // SEQ*2*FFN
    float* bias_cat = gu + (size_t)SEQ * 2 * FFN;            // QKVD
    float* ct       = bias_cat + QKVD;                       // SEQ*32
    float* st       = ct + (size_t)SEQ * 32;                 // SEQ*32
    // bf16 workspace
    ushort* xbf = (ushort*)(st + (size_t)SEQ * 32);          // SEQ*DIM
    ushort* obf = xbf + (size_t)SEQ * DIM;                   // SEQ*DIM
    ushort* gbf = obf + (size_t)SEQ * DIM;                   // SEQ*FFN
    ushort* wbf = gbf + (size_t)SEQ * FFN;                   // VOCAB*DIM (reused per layer)

    ushort* qkvT = wbf;                                      // [1536][1024]
    ushort* owT  = qkvT + (size_t)QKVD * DIM;                // [1024][1024]
    ushort* guT  = owT  + (size_t)DIM * DIM;                 // [8192][1024]
    ushort* dwT  = guT  + (size_t)2 * FFN * DIM;             // [1024][4096]

    k_rope_table<<<SEQ * 32 / 256, 256, 0, stream>>>(ct, st);
    k_embed<<<SEQ, 256, 0, stream>>>(emb, ids, h);

    dim3 tb(32, 8);
    for (int l = 0; l < LAY; l++) {
        const float* qw_l = qw + (size_t)l * DIM * NHQ * DH;
        const float* kw_l = kw + (size_t)l * DIM * NKV * DH;
        const float* vw_l = vw + (size_t)l * DIM * NKV * DH;
        const float* ow_l = ow + (size_t)l * NHQ * DH * DIM;
        const float* gw_l = gw + (size_t)l * DIM * FFN;
        const float* uw_l = uw + (size_t)l * DIM * FFN;
        const float* dw_l = dw + (size_t)l * FFN * DIM;

        k_rmsnorm<<<SEQ, 256, 0, stream>>>(h, ln1 + (size_t)l * DIM, xbf);

        k_convT<<<dim3(DIM/32, DIM/32), tb, 0, stream>>>(qw_l, qkvT, DIM, DIM);
        k_convT<<<dim3(NKV*DH/32, DIM/32), tb, 0, stream>>>(kw_l, qkvT + (size_t)NHQ*DH*DIM, DIM, NKV*DH);
        k_convT<<<dim3(NKV*DH/32, DIM/32), tb, 0, stream>>>(vw_l, qkvT + (size_t)(NHQ*DH+NKV*DH)*DIM, DIM, NKV*DH);
        k_bias_cat<<<(QKVD + 255) / 256, 256, 0, stream>>>(
            qbias + (size_t)l * NHQ * DH, kbias + (size_t)l * NKV * DH,
            vbias + (size_t)l * NKV * DH, bias_cat);
        k_gemm_bf<1,0><<<dim3(QKVD/128, SEQ/128), 256, 0, stream>>>(
            xbf, qkvT, bias_cat, qkv, SEQ, QKVD, DIM);

        k_rope<<<SEQ, 256, 0, stream>>>(qkv, ct, st);
        k_attn<<<dim3(SEQ/64, NHQ), 256, 0, stream>>>(qkv, obf);

        k_convT<<<dim3(DIM/32, DIM/32), tb, 0, stream>>>(ow_l, owT, DIM, DIM);
        k_gemm_bf<0,1><<<dim3(DIM/128, SEQ/128), 256, 0, stream>>>(
            obf, owT, nullptr, h, SEQ, DIM, DIM);

        k_rmsnorm<<<SEQ, 256, 0, stream>>>(h, ln2 + (size_t)l * DIM, xbf);

        k_convT<<<dim3(FFN/32, DIM/32), tb, 0, stream>>>(gw_l, guT, DIM, FFN);
        k_convT<<<dim3(FFN/32, DIM/32), tb, 0, stream>>>(uw_l, guT + (size_t)FFN*DIM, DIM, FFN);
        k_gemm_bf<0,0><<<dim3(2*FFN/128, SEQ/128), 256, 0, stream>>>(
            xbf, guT, nullptr, gu, SEQ, 2*FFN, DIM);
        k_silu_mul_bf<<<SEQ * FFN / 4 / 256, 256, 0, stream>>>(gu, gbf);

        k_convT<<<dim3(DIM/32, FFN/32), tb, 0, stream>>>(dw_l, dwT, FFN, DIM);
        k_gemm_bf<0,1><<<dim3(DIM/128, SEQ/128), 256, 0, stream>>>(
            gbf, dwT, nullptr, h, SEQ, DIM, FFN);
    }

    k_rmsnorm<<<SEQ, 256, 0, stream>>>(h, norm_w, xbf);
    k_convT<<<dim3(VOCAB/32, DIM/32), tb, 0, stream>>>(lm_w, wbf, DIM, VOCAB);
    k_gemm_bf<0,0><<<dim3(VOCAB/128, SEQ/128), 256, 0, stream>>>(
        xbf, wbf, nullptr, out, SEQ, VOCAB, DIM);
}